// Round 1
// 2537.510 us; speedup vs baseline: 1.2254x; 1.2254x over previous
//
#include <hip/hip_runtime.h>
#include <math.h>

#define H 256
#define R 8            // n-rows per block
#define RG 4           // n-rows per group (R/2)
#define AM (3*R)       // A-rows in block tile (24)
#define AMG (3*RG)     // A-rows per group (12)

// 256 threads = 2 groups of 128 (waves 0-1 = group 0, waves 2-3 = group 1).
// Group g owns n-rows {4g..4g+3}; thread tl owns columns {tl, tl+128}.
// GEMM1 outputs (vec1/vec2/scalar/vec_dot) live entirely in registers.
__global__ __launch_bounds__(256, 4) void fte_kernel(
    const float* __restrict__ x,
    const float* __restrict__ vec,
    const float* __restrict__ W_equi,
    const float* __restrict__ W1,
    const float* __restrict__ b1,
    const float* __restrict__ W2,
    const float* __restrict__ b2,
    float* __restrict__ dx,
    float* __restrict__ dvec,
    int N)
{
    // 24 KB, phase-reused:
    //   phase A: vec A-tile [AM][H]
    //   phase B: hin [R][2H] (first 16 KB) + h [R][H] (last 8 KB)
    __shared__ float smem[AM * H];

    const int t  = threadIdx.x;
    const int g  = t >> 7;           // group
    const int tl = t & 127;
    const int row0 = blockIdx.x * R;

    // ---- stage vec tile -> LDS ----
    {
        const int rem  = N - row0;
        const int rows = rem < R ? rem : R;
        const int total = rows * 3 * H;
        const float* src = vec + (size_t)row0 * 3 * H;
        if (total == AM * H) {
            const float4* s4 = (const float4*)src;
            float4* d4 = (float4*)smem;
            #pragma unroll
            for (int i = 0; i < 6; ++i) d4[t + 256 * i] = s4[t + 256 * i];
        } else {
            for (int i = t; i < total; i += 256) smem[i] = src[i];
            for (int i = total + t; i < AM * H; i += 256) smem[i] = 0.f;
        }
    }
    __syncthreads();

    // ---- GEMM1: rows [12g,12g+12) x cols {tl,tl+128} (+256 for vec2) ----
    float a1[AMG][2], a2[AMG][2];
    #pragma unroll
    for (int m = 0; m < AMG; ++m) {
        a1[m][0] = a1[m][1] = a2[m][0] = a2[m][1] = 0.f;
    }
    {
        const float* As = smem + AMG * H * g;
        const float* wbase = W_equi + tl;
        for (int k = 0; k < H; k += 4) {
            float w[4][4];
            #pragma unroll
            for (int u = 0; u < 4; ++u) {
                const float* wr = wbase + (size_t)(k + u) * (2 * H);
                w[u][0] = wr[0];
                w[u][1] = wr[128];
                w[u][2] = wr[256];
                w[u][3] = wr[384];
            }
            #pragma unroll
            for (int m = 0; m < AMG; ++m) {
                const float4 av = *(const float4*)&As[m * H + k];
                const float aa[4] = {av.x, av.y, av.z, av.w};
                #pragma unroll
                for (int u = 0; u < 4; ++u) {
                    a1[m][0] = fmaf(aa[u], w[u][0], a1[m][0]);
                    a1[m][1] = fmaf(aa[u], w[u][1], a1[m][1]);
                    a2[m][0] = fmaf(aa[u], w[u][2], a2[m][0]);
                    a2[m][1] = fmaf(aa[u], w[u][3], a2[m][1]);
                }
            }
        }
    }

    // ---- reductions fully in registers ----
    float sc[RG][2], vd[RG][2];
    #pragma unroll
    for (int nl = 0; nl < RG; ++nl) {
        #pragma unroll
        for (int jj = 0; jj < 2; ++jj) {
            float s = 0.f, d = 0.f;
            #pragma unroll
            for (int c = 0; c < 3; ++c) {
                const float u1 = a1[nl * 3 + c][jj];
                s = fmaf(u1, u1, s);
                d = fmaf(u1, a2[nl * 3 + c][jj], d);
            }
            sc[nl][jj] = sqrtf(s);
            vd[nl][jj] = d * 0.0625f;   // 1/sqrt(256)
        }
    }
    __syncthreads();   // A-tile reads done; repurpose smem

    // ---- build hin = [x | scalar] at smem[0..4096) ----
    #pragma unroll
    for (int nl = 0; nl < RG; ++nl) {
        smem[(4 * g + nl) * (2 * H) + H + tl]       = sc[nl][0];
        smem[(4 * g + nl) * (2 * H) + H + tl + 128] = sc[nl][1];
    }
    for (int i = t; i < R * (H / 4); i += 256) {
        const int nb = i >> 6;
        const int kq = i & 63;
        const int n = row0 + nb;
        float4 v = make_float4(0.f, 0.f, 0.f, 0.f);
        if (n < N) v = ((const float4*)x)[(size_t)n * (H / 4) + kq];
        *(float4*)&smem[nb * (2 * H) + kq * 4] = v;
    }
    __syncthreads();

    // ---- GEMM2: h = silu(hin @ W1 + b1), group's 4 rows x cols {tl,tl+128} ----
    float h2[RG][2];
    #pragma unroll
    for (int nl = 0; nl < RG; ++nl) { h2[nl][0] = h2[nl][1] = 0.f; }
    {
        const float* wbase = W1 + tl;
        for (int k = 0; k < 2 * H; k += 4) {
            float w[4][2];
            #pragma unroll
            for (int u = 0; u < 4; ++u) {
                const float* wr = wbase + (size_t)(k + u) * H;
                w[u][0] = wr[0];
                w[u][1] = wr[128];
            }
            #pragma unroll
            for (int nl = 0; nl < RG; ++nl) {
                const float4 av = *(const float4*)&smem[(4 * g + nl) * (2 * H) + k];
                const float aa[4] = {av.x, av.y, av.z, av.w};
                #pragma unroll
                for (int u = 0; u < 4; ++u) {
                    h2[nl][0] = fmaf(aa[u], w[u][0], h2[nl][0]);
                    h2[nl][1] = fmaf(aa[u], w[u][1], h2[nl][1]);
                }
            }
        }
    }
    {
        const float bv0 = b1[tl];
        const float bv1 = b1[tl + 128];
        #pragma unroll
        for (int nl = 0; nl < RG; ++nl) {
            const float z0 = h2[nl][0] + bv0;
            const float z1 = h2[nl][1] + bv1;
            smem[R * 2 * H + (4 * g + nl) * H + tl]       = z0 / (1.f + __expf(-z0));
            smem[R * 2 * H + (4 * g + nl) * H + tl + 128] = z1 / (1.f + __expf(-z1));
        }
    }
    __syncthreads();

    // ---- GEMM3: group's 4 rows x cols {tl,tl+128} x 3 outputs ----
    float a3[RG][2][3];
    #pragma unroll
    for (int nl = 0; nl < RG; ++nl)
        #pragma unroll
        for (int jj = 0; jj < 2; ++jj)
            a3[nl][jj][0] = a3[nl][jj][1] = a3[nl][jj][2] = 0.f;
    {
        const float* wbase = W2 + tl;
        for (int k = 0; k < H; k += 4) {
            float w[4][2][3];
            #pragma unroll
            for (int u = 0; u < 4; ++u) {
                const float* wr = wbase + (size_t)(k + u) * (3 * H);
                w[u][0][0] = wr[0];       w[u][0][1] = wr[H];       w[u][0][2] = wr[2 * H];
                w[u][1][0] = wr[128];     w[u][1][1] = wr[H + 128]; w[u][1][2] = wr[2 * H + 128];
            }
            #pragma unroll
            for (int nl = 0; nl < RG; ++nl) {
                const float4 av = *(const float4*)&smem[R * 2 * H + (4 * g + nl) * H + k];
                const float aa[4] = {av.x, av.y, av.z, av.w};
                #pragma unroll
                for (int u = 0; u < 4; ++u) {
                    #pragma unroll
                    for (int jj = 0; jj < 2; ++jj) {
                        a3[nl][jj][0] = fmaf(aa[u], w[u][jj][0], a3[nl][jj][0]);
                        a3[nl][jj][1] = fmaf(aa[u], w[u][jj][1], a3[nl][jj][1]);
                        a3[nl][jj][2] = fmaf(aa[u], w[u][jj][2], a3[nl][jj][2]);
                    }
                }
            }
        }
    }

    // ---- epilogue: everything register-local (vd, a2 pair with same j) ----
    const float iv2 = 0.70710678118654752440f;
    const float b2v[2][3] = {
        {b2[tl],       b2[H + tl],       b2[2 * H + tl]},
        {b2[tl + 128], b2[H + tl + 128], b2[2 * H + tl + 128]}
    };
    #pragma unroll
    for (int nl = 0; nl < RG; ++nl) {
        const int n = row0 + 4 * g + nl;
        if (n < N) {
            #pragma unroll
            for (int jj = 0; jj < 2; ++jj) {
                const int j = tl + 128 * jj;
                const float xv1 = a3[nl][jj][0] + b2v[jj][0];
                const float xv2 = a3[nl][jj][1] + b2v[jj][1];
                const float xv3 = a3[nl][jj][2] + b2v[jj][2];
                __builtin_nontemporal_store((xv1 + xv2 + vd[nl][jj]) * iv2,
                                            &dx[(size_t)n * H + j]);
                #pragma unroll
                for (int c = 0; c < 3; ++c) {
                    __builtin_nontemporal_store(xv3 * a2[nl * 3 + c][jj],
                                                &dvec[((size_t)n * 3 + c) * H + j]);
                }
            }
        }
    }
}

extern "C" void kernel_launch(void* const* d_in, const int* in_sizes, int n_in,
                              void* d_out, int out_size, void* d_ws, size_t ws_size,
                              hipStream_t stream) {
    const float* x      = (const float*)d_in[0];
    const float* vec    = (const float*)d_in[1];
    // d_in[2] = node_frame: unused by the reference computation
    const float* W_equi = (const float*)d_in[3];
    const float* W1     = (const float*)d_in[4];
    const float* b1     = (const float*)d_in[5];
    const float* W2     = (const float*)d_in[6];
    const float* b2     = (const float*)d_in[7];

    const int N = in_sizes[0] / H;
    float* dx   = (float*)d_out;
    float* dvec = (float*)d_out + (size_t)N * H;

    const int blocks = (N + R - 1) / R;
    fte_kernel<<<blocks, 256, 0, stream>>>(x, vec, W_equi, W1, b1, W2, b2, dx, dvec, N);
}